// Round 2
// baseline (276.746 us; speedup 1.0000x reference)
//
#include <hip/hip_runtime.h>
#include <float.h>

#define N_NODES   50000
#define N_EDGES   800000
#define INDIM1    128
#define HC        64
#define N_GRAPHS  64
#define NEG_SLOPE 0.2f
#define CAP       64      // slot capacity/node; deg~Poisson(16); validated R5-R14
#define CSTRIDE   16      // cursor: one counter per 64B line (R12: scatter 54->49us)

// Fused layer-1 grid geometry: 3:2 interleave of transform:scatter blocks (R15:
// scatter's latency-bound random writes drain UNDER transform's FMA compute;
// 298->269us). +1 rider block for the wedot precompute.
#define FGROUPS   521
#define FTBLK     (3 * FGROUPS)            // 1563 transform blocks
#define FSBLK     (2 * FGROUPS)            // 1042 scatter blocks
#define FGRID     (5 * FGROUPS + 1)        // 2606 total
#define ESTRIDE   (FSBLK * 256)            // 266752 edge stride

// ---------------- fused: layer-1 transform + CSR scatter + wedot rider -------
__global__ __launch_bounds__(256, 4) void fused1_kernel(const float* __restrict__ x,
                                                        const float* __restrict__ W,
                                                        const float* __restrict__ att_s,
                                                        const float* __restrict__ att_d,
                                                        float* __restrict__ xs,
                                                        float* __restrict__ a_src,
                                                        float* __restrict__ a_dst,
                                                        const int* __restrict__ src,
                                                        const int* __restrict__ dst,
                                                        const float* __restrict__ eattr,
                                                        int* __restrict__ cursor,
                                                        int2* __restrict__ csr_se,
                                                        const float* __restrict__ We1,
                                                        const float* __restrict__ ae1,
                                                        const float* __restrict__ We2,
                                                        const float* __restrict__ ae2,
                                                        float* __restrict__ wd) {
    constexpr int K4 = INDIM1 / 4;
    constexpr int NPW = 8;
    __shared__ float4 Wsh[K4 * 64];       // [k4][col]: 32KB
    __shared__ float4 xsh[4][2][K4];      // [wave][node-in-pair][k4]
    int bid = blockIdx.x;
    int t = threadIdx.x;

    if (bid == FGRID - 1) {
        // wedot rider block (R13-validated)
        if (t < 128) {
            const float* We = (t < 64) ? We1 : We2;
            const float* ae = (t < 64) ? ae1 : ae2;
            int l = t & 63;
            float p = We[l] * ae[l];
            for (int off = 1; off < 16; off <<= 1) p += __shfl_xor(p, off);
            if ((l & 15) == 0) wd[(t >> 6) * 4 + (l >> 4)] = p;
        }
        return;
    }

    int grp = bid / 5;
    int rem = bid - grp * 5;
    if (rem >= 3) {
        // ---- scatter path (block-uniform branch; returns before syncthreads)
        int sb = grp * 2 + (rem - 3);     // 0..1041
        for (int e = sb * 256 + t; e < N_EDGES; e += ESTRIDE) {
            int d = dst[e];
            int c = atomicAdd(&cursor[(size_t)d * CSTRIDE], 1);
            if (c < CAP)
                csr_se[(size_t)d * CAP + c] = make_int2(src[e], __float_as_int(eattr[e]));
        }
        return;
    }

    // ---- transform path, block id 0..1562
    int tb = grp * 3 + rem;
    for (int i = t; i < K4 * 64; i += 256) {
        int k4 = i >> 6, col = i & 63;
        Wsh[i] = make_float4(W[(4 * k4 + 0) * 64 + col], W[(4 * k4 + 1) * 64 + col],
                             W[(4 * k4 + 2) * 64 + col], W[(4 * k4 + 3) * 64 + col]);
    }
    __syncthreads();
    int w = t >> 6, lane = t & 63;
    float avs = att_s[lane], avd = att_d[lane];
    int node0 = tb * (4 * NPW) + w * NPW;
    for (int ng = 0; ng < NPW; ng += 2) {
        int nbase = node0 + ng;
        if (nbase >= N_NODES) return;     // wave-uniform
        for (int q = lane; q < 2 * K4; q += 64) {
            int nn = q / K4, kk = q - nn * K4;
            int node = nbase + nn;
            xsh[w][nn][kk] = (node < N_NODES)
                ? ((const float4*)(x + (size_t)node * INDIM1))[kk]
                : make_float4(0.f, 0.f, 0.f, 0.f);
        }
        float acc0 = 0.f, acc1 = 0.f;
#pragma unroll 4
        for (int k4 = 0; k4 < K4; ++k4) {
            float4 wv = Wsh[k4 * 64 + lane];          // 1 b128 read feeds 8 fmas
            float4 x0 = xsh[w][0][k4];
            float4 x1 = xsh[w][1][k4];
            acc0 = fmaf(x0.x, wv.x, acc0);
            acc0 = fmaf(x0.y, wv.y, acc0);
            acc0 = fmaf(x0.z, wv.z, acc0);
            acc0 = fmaf(x0.w, wv.w, acc0);
            acc1 = fmaf(x1.x, wv.x, acc1);
            acc1 = fmaf(x1.y, wv.y, acc1);
            acc1 = fmaf(x1.z, wv.z, acc1);
            acc1 = fmaf(x1.w, wv.w, acc1);
        }
#pragma unroll
        for (int nn = 0; nn < 2; ++nn) {
            int node = nbase + nn;
            if (node >= N_NODES) break;
            float a = nn ? acc1 : acc0;
            xs[(size_t)node * 64 + lane] = a;
            float ps = a * avs;
            float pd = a * avd;
            for (int off = 1; off < 16; off <<= 1) {
                ps += __shfl_xor(ps, off);
                pd += __shfl_xor(pd, off);
            }
            if ((lane & 15) == 0) {
                a_src[node * 4 + (lane >> 4)] = ps;
                a_dst[node * 4 + (lane >> 4)] = pd;
            }
        }
    }
}

// ---------------- fused attention + aggregation (+ optional layer-2 transform)
// FUSE=1 (layer 1): epilogue applies bias+relu, then computes h@W2 in-wave
// (W2 staged in LDS; each wave holds the full h-row across its 64 lanes),
// writes xs2 + layer-2 att dots. Removes the standalone transform2 dispatch
// and the hbuf roundtrip (R16 theory).
// FUSE=0 (layer 2): writes bias'd result for pooling.
// NB*4 == N_NODES exactly -> no early-return, the one __syncthreads is safe.
template <int FUSE>
__global__ __launch_bounds__(256) void aggregate_kernel(const float* __restrict__ xs,
                                                        const int2* __restrict__ csr_se,
                                                        const int* __restrict__ degp,
                                                        const float* __restrict__ a_src,
                                                        const float* __restrict__ a_dst,
                                                        const float* __restrict__ wd,
                                                        const float* __restrict__ bias,
                                                        float* __restrict__ outb,
                                                        const float* __restrict__ W2,
                                                        const float* __restrict__ as2,
                                                        const float* __restrict__ ad2,
                                                        float* __restrict__ asrc2,
                                                        float* __restrict__ adst2) {
    __shared__ float  W2sh[64 * 64];      // 16KB, used when FUSE=1
    __shared__ float4 hsh4[4][16];        // per-wave h-row staging
    int t = threadIdx.x;
    int w = t >> 6, lane = t & 63;
    float avs2 = 0.f, avd2 = 0.f;
    if (FUSE) {
        for (int i = t; i < 64 * 64; i += 256) W2sh[i] = W2[i];
        avs2 = as2[lane];
        avd2 = ad2[lane];
        __syncthreads();
    }
    int node = blockIdx.x * 4 + w;
    if (node >= N_NODES) return;
    int beg = node * CAP;
    int end = beg + min(degp[(size_t)node * CSTRIDE], CAP);
    const int e_idx = lane >> 2;
    const int h4 = lane & 3;
    const int h2 = lane >> 4;

    float wdv = wd[h4];
    float adv = a_dst[node * 4 + h4];

    float m = -FLT_MAX;
    float s = 0.f;
    float acc = 0.f;

    for (int j0 = beg; j0 < end; j0 += 16) {
        int j = j0 + e_idx;
        bool v = (j < end);
        int sv = 0;
        float a = -FLT_MAX;
        if (v) {
            int2 se = csr_se[j];
            sv = se.x;
            float ea = __int_as_float(se.y);
            float as = a_src[sv * 4 + h4];          // gather, 800KB L2-resident
            a = as + adv + ea * wdv;
            a = a > 0.f ? a : NEG_SLOPE * a;
        }
        float cm = a;
        cm = fmaxf(cm, __shfl_xor(cm, 4));
        cm = fmaxf(cm, __shfl_xor(cm, 8));
        cm = fmaxf(cm, __shfl_xor(cm, 16));
        cm = fmaxf(cm, __shfl_xor(cm, 32));
        float mn = fmaxf(m, cm);
        float sc = __expf(m - mn);
        float wgt = __expf(a - mn);                 // 0 for invalid slots
        s = s * sc + wgt;
        m = mn;
        acc *= __shfl(sc, h2);
#pragma unroll
        for (int e = 0; e < 16; ++e) {
            float wg = __shfl(wgt, (e << 2) | h2);
            int svb = __shfl(sv, e << 2);
            acc = fmaf(wg, xs[(size_t)svb * 64 + lane], acc);
        }
    }
    s += __shfl_xor(s, 4);
    s += __shfl_xor(s, 8);
    s += __shfl_xor(s, 16);
    s += __shfl_xor(s, 32);
    float sh = __shfl(s, h2);
    float res = (sh > 0.f) ? acc / sh : 0.f;
    res += bias[lane];

    if (FUSE) {
        // layer-2 transform fused: h = relu(res); out = h^T @ W2
        float h = fmaxf(res, 0.f);
        ((float*)&hsh4[w][0])[lane] = h;
        float acc2 = 0.f;
#pragma unroll
        for (int k4 = 0; k4 < 16; ++k4) {
            float4 hb = hsh4[w][k4];                 // wave-broadcast read
            acc2 = fmaf(hb.x, W2sh[(4 * k4 + 0) * 64 + lane], acc2);
            acc2 = fmaf(hb.y, W2sh[(4 * k4 + 1) * 64 + lane], acc2);
            acc2 = fmaf(hb.z, W2sh[(4 * k4 + 2) * 64 + lane], acc2);
            acc2 = fmaf(hb.w, W2sh[(4 * k4 + 3) * 64 + lane], acc2);
        }
        outb[(size_t)node * 64 + lane] = acc2;       // xs2
        float ps = acc2 * avs2;
        float pd = acc2 * avd2;
        for (int off = 1; off < 16; off <<= 1) {
            ps += __shfl_xor(ps, off);
            pd += __shfl_xor(pd, off);
        }
        if ((lane & 15) == 0) {
            asrc2[node * 4 + (lane >> 4)] = ps;
            adst2[node * 4 + (lane >> 4)] = pd;
        }
    } else {
        outb[(size_t)node * 64 + lane] = res;
    }
}

// ---------------- pooling (R12-proven) ----------------
__global__ __launch_bounds__(256) void pool_kernel(const float* __restrict__ h,
                                                   const int* __restrict__ batch,
                                                   float* __restrict__ out) {
    int wave = (blockIdx.x * blockDim.x + threadIdx.x) >> 6;
    int lane = threadIdx.x & 63;
    int i0 = wave * 16;
    if (i0 >= N_NODES) return;
    int i1 = min(i0 + 16, N_NODES);
    float acc = 0.f;
    int gcur = batch[i0];
    for (int i = i0; i < i1; ++i) {
        int g = batch[i];
        if (g != gcur) {
            atomicAdd(&out[gcur * 64 + lane], acc);
            acc = 0.f; gcur = g;
        }
        acc += h[i * 64 + lane];
    }
    atomicAdd(&out[gcur * 64 + lane], acc);
}

__global__ void pool_div_kernel(float* __restrict__ out, const int* __restrict__ batch) {
    int g = blockIdx.x, t = threadIdx.x;
    int lo = 0, hi = N_NODES;
    while (lo < hi) { int mid = (lo + hi) >> 1; if (batch[mid] < g) lo = mid + 1; else hi = mid; }
    int lo2 = lo, hi2 = N_NODES;
    while (lo2 < hi2) { int mid = (lo2 + hi2) >> 1; if (batch[mid] <= g) lo2 = mid + 1; else hi2 = mid; }
    float c = (float)max(lo2 - lo, 1);
    out[g * 64 + t] /= c;
}

// ---------------- launch ----------------

extern "C" void kernel_launch(void* const* d_in, const int* in_sizes, int n_in,
                              void* d_out, int out_size, void* d_ws, size_t ws_size,
                              hipStream_t stream) {
    const float* x    = (const float*)d_in[0];
    const int*   eidx = (const int*)d_in[1];
    const float* eat  = (const float*)d_in[2];
    const int*   batch= (const int*)d_in[3];
    const float* W1   = (const float*)d_in[4];
    const float* We1  = (const float*)d_in[5];
    const float* as1  = (const float*)d_in[6];
    const float* ad1  = (const float*)d_in[7];
    const float* ae1  = (const float*)d_in[8];
    const float* b1   = (const float*)d_in[9];
    const float* W2   = (const float*)d_in[10];
    const float* We2  = (const float*)d_in[11];
    const float* as2  = (const float*)d_in[12];
    const float* ad2  = (const float*)d_in[13];
    const float* ae2  = (const float*)d_in[14];
    const float* b2   = (const float*)d_in[15];
    const int* src  = eidx;             // edge_index[0]
    const int* dstp = eidx + N_EDGES;   // edge_index[1]
    float* out = (float*)d_out;

    char* p = (char*)d_ws;
    auto alloc = [&](size_t bytes) {
        char* r = p;
        p += (bytes + 255) & ~(size_t)255;
        return r;
    };
    int2*  csrse  = (int2*)alloc((size_t)N_NODES * CAP * 8);       // 25.6 MB
    float* xs     = (float*)alloc((size_t)N_NODES * 64 * 4);       // buffer A
    float* hbuf   = (float*)alloc((size_t)N_NODES * 64 * 4);       // buffer C (xs2)
    float* asrc   = (float*)alloc((size_t)N_NODES * 4 * 4);
    float* adst   = (float*)alloc((size_t)N_NODES * 4 * 4);
    float* asrc2  = (float*)alloc((size_t)N_NODES * 4 * 4);
    float* adst2  = (float*)alloc((size_t)N_NODES * 4 * 4);
    float* wd     = (float*)alloc(64);                             // wd1[4] || wd2[4]
    int*   cursor = (int*)alloc((size_t)N_NODES * CSTRIDE * 4);    // 3.2 MB padded

    hipMemsetAsync(cursor, 0, (size_t)N_NODES * CSTRIDE * 4, stream);
    hipMemsetAsync(d_out, 0, (size_t)N_GRAPHS * 64 * 4, stream);

    const int NB = (N_NODES + 3) / 4;                      // 12500 (×4 == N_NODES)

    // layer 1: fused transform + CSR scatter + wedot rider (R15)
    fused1_kernel<<<FGRID, 256, 0, stream>>>(x, W1, as1, ad1, xs, asrc, adst,
                                             src, dstp, eat, cursor, csrse,
                                             We1, ae1, We2, ae2, wd);
    // aggregate layer 1 + fused layer-2 transform (R16)
    aggregate_kernel<1><<<NB, 256, 0, stream>>>(xs, csrse, cursor, asrc, adst,
                                                wd, b1, hbuf,
                                                W2, as2, ad2, asrc2, adst2);
    // aggregate layer 2 -> final node features into xs (layer-1 xs is dead)
    aggregate_kernel<0><<<NB, 256, 0, stream>>>(hbuf, csrse, cursor, asrc2, adst2,
                                                wd + 4, b2, xs,
                                                nullptr, nullptr, nullptr, nullptr, nullptr);
    // mean pool (R12-proven)
    int pool_waves = (N_NODES + 15) / 16;
    int pool_blocks = (pool_waves + 3) / 4;
    pool_kernel<<<pool_blocks, 256, 0, stream>>>(xs, batch, out);
    pool_div_kernel<<<N_GRAPHS, 64, 0, stream>>>(out, batch);
}

// Round 3
// 250.488 us; speedup vs baseline: 1.1048x; 1.1048x over previous
//
#include <hip/hip_runtime.h>
#include <float.h>

#define N_NODES   50000
#define N_EDGES   800000
#define INDIM1    128
#define HC        64
#define N_GRAPHS  64
#define NEG_SLOPE 0.2f
#define CAP       64      // slot capacity/node; deg~Poisson(16); validated R5-R14
#define CSTRIDE   16      // cursor: one counter per 64B line (R12: scatter 54->49us)

// Fused layer-1 grid geometry: 3:2 interleave of transform:scatter blocks (R15:
// scatter's latency-bound random writes drain UNDER transform's FMA compute;
// 298->269us). +1 rider block for the wedot precompute.
#define FGROUPS   521
#define FTBLK     (3 * FGROUPS)            // 1563 transform blocks
#define FSBLK     (2 * FGROUPS)            // 1042 scatter blocks
#define FGRID     (5 * FGROUPS + 1)        // 2606 total
#define ESTRIDE   (FSBLK * 256)            // 266752 edge stride

// ---------------- fused: layer-1 transform + CSR scatter + wedot rider -------
__global__ __launch_bounds__(256, 4) void fused1_kernel(const float* __restrict__ x,
                                                        const float* __restrict__ W,
                                                        const float* __restrict__ att_s,
                                                        const float* __restrict__ att_d,
                                                        float* __restrict__ xs,
                                                        float* __restrict__ a_src,
                                                        float* __restrict__ a_dst,
                                                        const int* __restrict__ src,
                                                        const int* __restrict__ dst,
                                                        const float* __restrict__ eattr,
                                                        int* __restrict__ cursor,
                                                        int2* __restrict__ csr_se,
                                                        const float* __restrict__ We1,
                                                        const float* __restrict__ ae1,
                                                        const float* __restrict__ We2,
                                                        const float* __restrict__ ae2,
                                                        float* __restrict__ wd) {
    constexpr int K4 = INDIM1 / 4;
    constexpr int NPW = 8;
    __shared__ float4 Wsh[K4 * 64];       // [k4][col]: 32KB
    __shared__ float4 xsh[4][2][K4];      // [wave][node-in-pair][k4]
    int bid = blockIdx.x;
    int t = threadIdx.x;

    if (bid == FGRID - 1) {
        // wedot rider block (R13-validated)
        if (t < 128) {
            const float* We = (t < 64) ? We1 : We2;
            const float* ae = (t < 64) ? ae1 : ae2;
            int l = t & 63;
            float p = We[l] * ae[l];
            for (int off = 1; off < 16; off <<= 1) p += __shfl_xor(p, off);
            if ((l & 15) == 0) wd[(t >> 6) * 4 + (l >> 4)] = p;
        }
        return;
    }

    int grp = bid / 5;
    int rem = bid - grp * 5;
    if (rem >= 3) {
        // ---- scatter path (block-uniform branch; returns before syncthreads)
        int sb = grp * 2 + (rem - 3);     // 0..1041
        for (int e = sb * 256 + t; e < N_EDGES; e += ESTRIDE) {
            int d = dst[e];
            int c = atomicAdd(&cursor[(size_t)d * CSTRIDE], 1);
            if (c < CAP)
                csr_se[(size_t)d * CAP + c] = make_int2(src[e], __float_as_int(eattr[e]));
        }
        return;
    }

    // ---- transform path, block id 0..1562
    int tb = grp * 3 + rem;
    for (int i = t; i < K4 * 64; i += 256) {
        int k4 = i >> 6, col = i & 63;
        Wsh[i] = make_float4(W[(4 * k4 + 0) * 64 + col], W[(4 * k4 + 1) * 64 + col],
                             W[(4 * k4 + 2) * 64 + col], W[(4 * k4 + 3) * 64 + col]);
    }
    __syncthreads();
    int w = t >> 6, lane = t & 63;
    float avs = att_s[lane], avd = att_d[lane];
    int node0 = tb * (4 * NPW) + w * NPW;
    for (int ng = 0; ng < NPW; ng += 2) {
        int nbase = node0 + ng;
        if (nbase >= N_NODES) return;     // wave-uniform
        for (int q = lane; q < 2 * K4; q += 64) {
            int nn = q / K4, kk = q - nn * K4;
            int node = nbase + nn;
            xsh[w][nn][kk] = (node < N_NODES)
                ? ((const float4*)(x + (size_t)node * INDIM1))[kk]
                : make_float4(0.f, 0.f, 0.f, 0.f);
        }
        float acc0 = 0.f, acc1 = 0.f;
#pragma unroll 4
        for (int k4 = 0; k4 < K4; ++k4) {
            float4 wv = Wsh[k4 * 64 + lane];          // 1 b128 read feeds 8 fmas
            float4 x0 = xsh[w][0][k4];
            float4 x1 = xsh[w][1][k4];
            acc0 = fmaf(x0.x, wv.x, acc0);
            acc0 = fmaf(x0.y, wv.y, acc0);
            acc0 = fmaf(x0.z, wv.z, acc0);
            acc0 = fmaf(x0.w, wv.w, acc0);
            acc1 = fmaf(x1.x, wv.x, acc1);
            acc1 = fmaf(x1.y, wv.y, acc1);
            acc1 = fmaf(x1.z, wv.z, acc1);
            acc1 = fmaf(x1.w, wv.w, acc1);
        }
#pragma unroll
        for (int nn = 0; nn < 2; ++nn) {
            int node = nbase + nn;
            if (node >= N_NODES) break;
            float a = nn ? acc1 : acc0;
            xs[(size_t)node * 64 + lane] = a;
            float ps = a * avs;
            float pd = a * avd;
            for (int off = 1; off < 16; off <<= 1) {
                ps += __shfl_xor(ps, off);
                pd += __shfl_xor(pd, off);
            }
            if ((lane & 15) == 0) {
                a_src[node * 4 + (lane >> 4)] = ps;
                a_dst[node * 4 + (lane >> 4)] = pd;
            }
        }
    }
}

// ---------------- node transform (layer 2): 2-node blocking (R1-proven) ------
template <int INDIM, int NPW>
__global__ __launch_bounds__(256, 4) void transform_kernel(const float* __restrict__ x,
                                                           const float* __restrict__ W,
                                                           const float* __restrict__ att_s,
                                                           const float* __restrict__ att_d,
                                                           float* __restrict__ xs,
                                                           float* __restrict__ a_src,
                                                           float* __restrict__ a_dst) {
    constexpr int K4 = INDIM / 4;
    __shared__ float4 Wsh[K4 * 64];       // 16KB @64
    __shared__ float4 xsh[4][2][K4];
    int t = threadIdx.x;
    for (int i = t; i < K4 * 64; i += 256) {
        int k4 = i >> 6, col = i & 63;
        Wsh[i] = make_float4(W[(4 * k4 + 0) * 64 + col], W[(4 * k4 + 1) * 64 + col],
                             W[(4 * k4 + 2) * 64 + col], W[(4 * k4 + 3) * 64 + col]);
    }
    __syncthreads();
    int w = t >> 6, lane = t & 63;
    float avs = att_s[lane], avd = att_d[lane];
    int node0 = blockIdx.x * (4 * NPW) + w * NPW;
    for (int ng = 0; ng < NPW; ng += 2) {
        int nbase = node0 + ng;
        if (nbase >= N_NODES) return;     // wave-uniform
        for (int q = lane; q < 2 * K4; q += 64) {
            int nn = q / K4, kk = q - nn * K4;
            int node = nbase + nn;
            xsh[w][nn][kk] = (node < N_NODES)
                ? ((const float4*)(x + (size_t)node * INDIM))[kk]
                : make_float4(0.f, 0.f, 0.f, 0.f);
        }
        float acc0 = 0.f, acc1 = 0.f;
#pragma unroll 4
        for (int k4 = 0; k4 < K4; ++k4) {
            float4 wv = Wsh[k4 * 64 + lane];
            float4 x0 = xsh[w][0][k4];
            float4 x1 = xsh[w][1][k4];
            acc0 = fmaf(x0.x, wv.x, acc0);
            acc0 = fmaf(x0.y, wv.y, acc0);
            acc0 = fmaf(x0.z, wv.z, acc0);
            acc0 = fmaf(x0.w, wv.w, acc0);
            acc1 = fmaf(x1.x, wv.x, acc1);
            acc1 = fmaf(x1.y, wv.y, acc1);
            acc1 = fmaf(x1.z, wv.z, acc1);
            acc1 = fmaf(x1.w, wv.w, acc1);
        }
#pragma unroll
        for (int nn = 0; nn < 2; ++nn) {
            int node = nbase + nn;
            if (node >= N_NODES) break;
            float a = nn ? acc1 : acc0;
            xs[(size_t)node * 64 + lane] = a;
            float ps = a * avs;
            float pd = a * avd;
            for (int off = 1; off < 16; off <<= 1) {
                ps += __shfl_xor(ps, off);
                pd += __shfl_xor(pd, off);
            }
            if ((lane & 15) == 0) {
                a_src[node * 4 + (lane >> 4)] = ps;
                a_dst[node * 4 + (lane >> 4)] = pd;
            }
        }
    }
}

// ---------------- fused attention + aggregation: 2 nodes/wave (R17) ----------
// Latency-bound (R2 counters: 17% HBM, 41% VALU, 81us vs 17us BW-floor).
// (a) 2 independent per-node chains per wave -> ~32 gather loads in flight;
// (b) readlane puts the wave-uniform src row index in SGPR -> addressing on
//     the scalar pipe (e-loop: 1 bpermute + 1 fma per edge);
// (c) POOL=1: mean-pool fused into epilogue (batch sorted -> block-uniform
//     graph 99%: LDS combine + 1 atomic/block/channel); no node-feature write.
// Grid covers exactly N_NODES (6250*8) -> no early return; barrier is safe.
template <int POOL>
__global__ __launch_bounds__(256, 6) void aggregate_kernel(const float* __restrict__ xs,
                                                           const int2* __restrict__ csr_se,
                                                           const int* __restrict__ degp,
                                                           const float* __restrict__ a_src,
                                                           const float* __restrict__ a_dst,
                                                           const float* __restrict__ wd,
                                                           const float* __restrict__ bias,
                                                           float* __restrict__ outb,
                                                           int do_relu,
                                                           const int* __restrict__ batch,
                                                           float* __restrict__ gout) {
    __shared__ float plds[256];
    int t = threadIdx.x;
    int w = t >> 6, lane = t & 63;
    const int e_idx = lane >> 2;
    const int h4 = lane & 3;
    const int h2 = lane >> 4;
    int nodeA = blockIdx.x * 8 + w * 2;
    int nodeB = nodeA + 1;

    float wdv = wd[h4];
    float bv = bias[lane];
    float advA = a_dst[nodeA * 4 + h4];
    float advB = a_dst[nodeB * 4 + h4];
    int nA = min(degp[(size_t)nodeA * CSTRIDE], CAP);
    int nB = min(degp[(size_t)nodeB * CSTRIDE], CAP);
    int begA = nodeA * CAP, endA = begA + nA;
    int begB = nodeB * CAP, endB = begB + nB;

    float mA = -FLT_MAX, sA = 0.f, accA = 0.f;
    float mB = -FLT_MAX, sB = 0.f, accB = 0.f;

    auto alpha_phase = [&](int beg, int end, int it, float adv,
                           float& m, float& s, float& acc, int& sv, float& wgt) {
        int j = beg + it * 16 + e_idx;
        bool v = j < end;
        sv = 0;
        float a = -FLT_MAX;
        if (v) {
            int2 se = csr_se[j];
            sv = se.x;
            float ea = __int_as_float(se.y);
            float as = a_src[sv * 4 + h4];          // gather, 800KB L2-resident
            a = as + adv + ea * wdv;
            a = a > 0.f ? a : NEG_SLOPE * a;
        }
        float cm = a;
        cm = fmaxf(cm, __shfl_xor(cm, 4));
        cm = fmaxf(cm, __shfl_xor(cm, 8));
        cm = fmaxf(cm, __shfl_xor(cm, 16));
        cm = fmaxf(cm, __shfl_xor(cm, 32));
        float mn = fmaxf(m, cm);
        float sc = __expf(m - mn);
        wgt = __expf(a - mn);                       // 0 for invalid slots
        s = s * sc + wgt;
        m = mn;
        acc *= __shfl(sc, h2);
    };
    auto gather_phase = [&](int sv, float wgt, float& acc) {
#pragma unroll
        for (int e = 0; e < 16; ++e) {
            int svb = __builtin_amdgcn_readlane(sv, e << 2);   // SGPR row index
            float wg = __shfl(wgt, (e << 2) | h2);
            acc = fmaf(wg, xs[(size_t)svb * 64 + lane], acc);
        }
    };

    int itA = (nA + 15) >> 4, itB = (nB + 15) >> 4;
    int itC = min(itA, itB);
    for (int it = 0; it < itC; ++it) {
        int svA, svB; float wgtA, wgtB;
        alpha_phase(begA, endA, it, advA, mA, sA, accA, svA, wgtA);
        alpha_phase(begB, endB, it, advB, mB, sB, accB, svB, wgtB);
        gather_phase(svA, wgtA, accA);
        gather_phase(svB, wgtB, accB);
    }
    for (int it = itC; it < itA; ++it) {
        int svA; float wgtA;
        alpha_phase(begA, endA, it, advA, mA, sA, accA, svA, wgtA);
        gather_phase(svA, wgtA, accA);
    }
    for (int it = itC; it < itB; ++it) {
        int svB; float wgtB;
        alpha_phase(begB, endB, it, advB, mB, sB, accB, svB, wgtB);
        gather_phase(svB, wgtB, accB);
    }

    auto finish = [&](float s, float acc) {
        s += __shfl_xor(s, 4);
        s += __shfl_xor(s, 8);
        s += __shfl_xor(s, 16);
        s += __shfl_xor(s, 32);
        float sh = __shfl(s, h2);
        float res = (sh > 0.f) ? acc / sh : 0.f;
        return res + bv;
    };
    float resA = finish(sA, accA);
    float resB = finish(sB, accB);

    if (POOL) {
        int gA = batch[nodeA], gB = batch[nodeB];
        int gF = batch[blockIdx.x * 8];
        int gL = batch[blockIdx.x * 8 + 7];
        if (gF == gL) {                             // block-uniform branch
            plds[w * 64 + lane] = resA + resB;
            __syncthreads();
            if (w == 0) {
                float v = plds[lane] + plds[64 + lane] +
                          plds[128 + lane] + plds[192 + lane];
                atomicAdd(&gout[gF * 64 + lane], v);
            }
        } else {
            if (gA == gB) {
                atomicAdd(&gout[gA * 64 + lane], resA + resB);
            } else {
                atomicAdd(&gout[gA * 64 + lane], resA);
                atomicAdd(&gout[gB * 64 + lane], resB);
            }
        }
    } else {
        if (do_relu) { resA = fmaxf(resA, 0.f); resB = fmaxf(resB, 0.f); }
        outb[(size_t)nodeA * 64 + lane] = resA;
        outb[(size_t)nodeB * 64 + lane] = resB;
    }
}

__global__ void pool_div_kernel(float* __restrict__ out, const int* __restrict__ batch) {
    int g = blockIdx.x, t = threadIdx.x;
    int lo = 0, hi = N_NODES;
    while (lo < hi) { int mid = (lo + hi) >> 1; if (batch[mid] < g) lo = mid + 1; else hi = mid; }
    int lo2 = lo, hi2 = N_NODES;
    while (lo2 < hi2) { int mid = (lo2 + hi2) >> 1; if (batch[mid] <= g) lo2 = mid + 1; else hi2 = mid; }
    float c = (float)max(lo2 - lo, 1);
    out[g * 64 + t] /= c;
}

// ---------------- launch ----------------

extern "C" void kernel_launch(void* const* d_in, const int* in_sizes, int n_in,
                              void* d_out, int out_size, void* d_ws, size_t ws_size,
                              hipStream_t stream) {
    const float* x    = (const float*)d_in[0];
    const int*   eidx = (const int*)d_in[1];
    const float* eat  = (const float*)d_in[2];
    const int*   batch= (const int*)d_in[3];
    const float* W1   = (const float*)d_in[4];
    const float* We1  = (const float*)d_in[5];
    const float* as1  = (const float*)d_in[6];
    const float* ad1  = (const float*)d_in[7];
    const float* ae1  = (const float*)d_in[8];
    const float* b1   = (const float*)d_in[9];
    const float* W2   = (const float*)d_in[10];
    const float* We2  = (const float*)d_in[11];
    const float* as2  = (const float*)d_in[12];
    const float* ad2  = (const float*)d_in[13];
    const float* ae2  = (const float*)d_in[14];
    const float* b2   = (const float*)d_in[15];
    const int* src  = eidx;             // edge_index[0]
    const int* dstp = eidx + N_EDGES;   // edge_index[1]
    float* out = (float*)d_out;

    char* p = (char*)d_ws;
    auto alloc = [&](size_t bytes) {
        char* r = p;
        p += (bytes + 255) & ~(size_t)255;
        return r;
    };
    int2*  csrse  = (int2*)alloc((size_t)N_NODES * CAP * 8);       // 25.6 MB
    float* xs     = (float*)alloc((size_t)N_NODES * 64 * 4);
    float* hbuf   = (float*)alloc((size_t)N_NODES * 64 * 4);
    float* asrc   = (float*)alloc((size_t)N_NODES * 4 * 4);
    float* adst   = (float*)alloc((size_t)N_NODES * 4 * 4);
    float* wd     = (float*)alloc(64);                             // wd1[4] || wd2[4]
    int*   cursor = (int*)alloc((size_t)N_NODES * CSTRIDE * 4);    // 3.2 MB padded

    hipMemsetAsync(cursor, 0, (size_t)N_NODES * CSTRIDE * 4, stream);
    hipMemsetAsync(d_out, 0, (size_t)N_GRAPHS * 64 * 4, stream);

    const int NPW = 8;
    const int TB = (N_NODES + 4 * NPW - 1) / (4 * NPW);    // 1563
    const int NB = N_NODES / 8;                            // 6250 (×8 == N_NODES)

    // layer 1: fused transform + CSR scatter + wedot rider (R15)
    fused1_kernel<<<FGRID, 256, 0, stream>>>(x, W1, as1, ad1, xs, asrc, adst,
                                             src, dstp, eat, cursor, csrse,
                                             We1, ae1, We2, ae2, wd);
    // aggregate layer 1 -> hbuf (relu'd)
    aggregate_kernel<0><<<NB, 256, 0, stream>>>(xs, csrse, cursor, asrc, adst,
                                                wd, b1, hbuf, 1, nullptr, nullptr);
    // layer-2 transform (standalone; R2 lesson: in-aggregate W2 fusion costs
    // 200MB of per-block W2 staging and regresses)
    transform_kernel<HC, NPW><<<TB, 256, 0, stream>>>(hbuf, W2, as2, ad2, xs, asrc, adst);
    // aggregate layer 2 + fused mean-pool
    aggregate_kernel<1><<<NB, 256, 0, stream>>>(xs, csrse, cursor, asrc, adst,
                                                wd + 4, b2, nullptr, 0, batch, out);
    pool_div_kernel<<<N_GRAPHS, 64, 0, stream>>>(out, batch);
}